// Round 14
// baseline (315.309 us; speedup 1.0000x reference)
//
#include <hip/hip_runtime.h>
#include <hip/hip_bf16.h>

// Problem constants (B=4, C=64, N=8192, K=16, D=64)
#define NPTS 8192
#define NQ   32768      // B*N
#define KNN  16
#define SCAP 112        // survivor cap per query (expected ~25-50)

// ws layout (bytes)
#define OFF_XT   0                      // B*N*C f32 = 8 MB  (x transposed to (B,N,C))
#define OFF_FBIG (8*1024*1024)          // 17*64*64 f32 = 278528 B (F with appended -sum(F))
#define OFF_SUMS (OFF_FBIG + 278528)    // 128 f32 (sum, sumsq per channel)
#define OFF_IDX  (OFF_SUMS + 512)       // B*N*16 int32 = 2 MB
#define OFF_PRE  (OFF_IDX + 2*1024*1024)// B*N*64 f32 = 8 MB (pre-BN output, (B*N, D))
// sq array (B*N f32 = 128 KB) ALIASES the start of PRE: k_prep writes it,
// k_knn consumes it, then k_conv overwrites PRE — stream-ordered, safe.
#define OFF_SQ   OFF_PRE

typedef float v2f __attribute__((ext_vector_type(2)));
__device__ __forceinline__ v2f sp2(float v) { return (v2f){v, v}; }
__device__ __forceinline__ v2f fma2(v2f a, v2f b, v2f c) {
    return __builtin_elementwise_fma(a, b, c);
}
__device__ __forceinline__ v2f max2(v2f a, v2f b) {
    return __builtin_elementwise_max(a, b);
}

// Reference fp32 key — numpy execution model (verified R6, absmax 0.0156):
//   sq[m]   = (x*x + y*y) + z*z                  -- non-fused (np.sum(pos*pos))
//   inner   = fma(z,z', fma(y,y', rnd(x*x')))    -- einsum AVX2 axpy FMA chain
//   negd    = ((2*inner) - sq_n) - sq_m          -- elementwise, left-to-right
__device__ __forceinline__ float sq3(float x, float y, float z) {
    #pragma clang fp contract(off)
    float xx = x * x;
    float yy = y * y;
    float zz = z * z;
    return (xx + yy) + zz;
}
__device__ __forceinline__ float negd2(float qx, float qy, float qz, float sqn,
                                       float mx, float my, float mz, float sqm) {
    #pragma clang fp contract(off)
    float p0 = qx * mx;
    float inn = __builtin_fmaf(qz, mz, __builtin_fmaf(qy, my, p0));
    float t = 2.0f * inn;
    float u = t - sqn;
    return u - sqm;
}
// Filter margin: cheap fused key c~ = 2<q,m> - sqm differs from (exact key +
// sqn) by <= ~1e-4. 2e-3 is 20x conservative; two eps-steps cover tau-side
// and member-side error -> survivor set provably supersets the true top-16.
#define KEY_EPS2 2.0e-3f

// ---------------- K0: merged prep (transpose x | Fbig | zero sums | sq) ------
__global__ __launch_bounds__(256) void k_prep(const float* __restrict__ x,
                                              const float* __restrict__ F,
                                              const float* __restrict__ pos,
                                              float* __restrict__ xT,
                                              float* __restrict__ Fb,
                                              float* __restrict__ sums,
                                              float* __restrict__ sqa) {
    int bid = blockIdx.x;
    if (bid < 512) {
        __shared__ float tile[64][65];
        int lane = threadIdx.x & 63, wid = threadIdx.x >> 6;
        int b = bid >> 7, nt = bid & 127;
        int n0 = nt * 64;
        for (int rr = 0; rr < 16; ++rr) {
            int c = wid * 16 + rr;
            tile[c][lane] = x[((size_t)b * 64 + c) * NPTS + n0 + lane];
        }
        __syncthreads();
        for (int rr = 0; rr < 16; ++rr) {
            int r = wid * 16 + rr;
            xT[((size_t)(b * NPTS + n0 + r)) * 64 + lane] = tile[lane][r];
        }
    } else if (bid < 528) {
        int j = bid - 512;
        for (int e = threadIdx.x; e < 4096; e += 256)
            Fb[j * 4096 + e] = F[j * 4096 + e];
    } else if (bid == 528) {
        for (int e = threadIdx.x; e < 4096; e += 256) {
            float s = 0.f;
            for (int k = 0; k < 16; ++k) s += F[k * 4096 + e];
            Fb[16 * 4096 + e] = -s;
        }
    } else if (bid == 529) {
        if (threadIdx.x < 128) sums[threadIdx.x] = 0.f;
    } else {
        int g = (bid - 530) * 256 + threadIdx.x;   // 0..NQ-1
        int b = g >> 13, n = g & (NPTS - 1);
        const float* pb = pos + (size_t)b * 3 * NPTS;
        sqa[g] = sq3(pb[n], pb[NPTS + n], pb[2 * NPTS + n]);
    }
}

// ---------------- K1: kNN, 8 q/wave, packed-f32 key math ---------------------
// R13 lesson: VGPR=60, no spills — the 86 µs VALU invariant is the scalar
// instruction stream itself. Fix: pair queries into v2f and evaluate keys
// with v_pk_fma_f32 (3 pk_fma per candidate per query-PAIR vs 6 scalar FMA).
// Component-wise pk_fma is bit-identical IEEE fma -> same key bits, same
// tau/superset logic, same exact rerank.
__global__ __launch_bounds__(256, 4) void k_knn(const float* __restrict__ pos,
                                                const float* __restrict__ sqa,
                                                int* __restrict__ idxo) {
    __shared__ int            cnt[32];
    __shared__ unsigned short sidx[32][SCAP];
    __shared__ float          skey[32][SCAP];
    __shared__ int            outI[32][16];
    int t = threadIdx.x, lane = t & 63, wid = t >> 6;
    int qblk = blockIdx.x * 32;               // 32 queries per block, same batch
    int b = qblk >> 13;
    const float* px = pos + (size_t)b * 3 * NPTS;
    const float* py = px + NPTS;
    const float* pz = py + NPTS;
    const float* sb = sqa + (size_t)b * NPTS;
    int n0 = (qblk & (NPTS - 1)) + wid * 8;   // this wave's first query

    float qxs[8], qys[8], qzs[8], sqs[8];
    #pragma unroll
    for (int i = 0; i < 8; ++i) {
        qxs[i] = px[n0 + i]; qys[i] = py[n0 + i]; qzs[i] = pz[n0 + i];
        sqs[i] = sb[n0 + i];
    }
    v2f tqx2[4], tqy2[4], tqz2[4];
    #pragma unroll
    for (int p = 0; p < 4; ++p) {
        tqx2[p] = (v2f){2.0f * qxs[2*p], 2.0f * qxs[2*p+1]};
        tqy2[p] = (v2f){2.0f * qys[2*p], 2.0f * qys[2*p+1]};
        tqz2[p] = (v2f){2.0f * qzs[2*p], 2.0f * qzs[2*p+1]};
    }
    if (lane < 8) cnt[wid * 8 + lane] = 0;    // wave-private lists
    if (lane < 16) {
        #pragma unroll
        for (int i = 0; i < 8; ++i) outI[wid * 8 + i][lane] = n0 + i;  // fallback
    }

    // pass 1: per-lane max of cheap key per query pair (pk math)
    v2f lm2[4];
    #pragma unroll
    for (int p = 0; p < 4; ++p) lm2[p] = sp2(-3.4e38f);
    for (int it = 0; it < 32; ++it) {
        int m = it * 256 + lane * 4;
        float4 X = *(const float4*)(px + m);
        float4 Y = *(const float4*)(py + m);
        float4 Z = *(const float4*)(pz + m);
        float4 S = *(const float4*)(sb + m);
        float n0s = -S.x, n1s = -S.y, n2s = -S.z, n3s = -S.w;
        #pragma unroll
        for (int p = 0; p < 4; ++p) {
            v2f k0 = fma2(tqx2[p], sp2(X.x), fma2(tqy2[p], sp2(Y.x), fma2(tqz2[p], sp2(Z.x), sp2(n0s))));
            v2f k1 = fma2(tqx2[p], sp2(X.y), fma2(tqy2[p], sp2(Y.y), fma2(tqz2[p], sp2(Z.y), sp2(n1s))));
            v2f k2 = fma2(tqx2[p], sp2(X.z), fma2(tqy2[p], sp2(Y.z), fma2(tqz2[p], sp2(Z.z), sp2(n2s))));
            v2f k3 = fma2(tqx2[p], sp2(X.w), fma2(tqy2[p], sp2(Y.w), fma2(tqz2[p], sp2(Z.w), sp2(n3s))));
            v2f m01 = max2(k0, k1), m23 = max2(k2, k3);
            lm2[p] = max2(lm2[p], max2(m01, m23));
        }
    }

    // thr[i] = (16th largest of 64 lane maxima) - 2*eps
    float thr[8];
    #pragma unroll
    for (int i = 0; i < 8; ++i) {
        float val = (i & 1) ? lm2[i >> 1].y : lm2[i >> 1].x;
        float tv = 0.f;
        for (int r = 0; r < 16; ++r) {
            float mm = val;
            mm = fmaxf(mm, __shfl_xor(mm, 1, 64));
            mm = fmaxf(mm, __shfl_xor(mm, 2, 64));
            mm = fmaxf(mm, __shfl_xor(mm, 4, 64));
            mm = fmaxf(mm, __shfl_xor(mm, 8, 64));
            mm = fmaxf(mm, __shfl_xor(mm, 16, 64));
            mm = fmaxf(mm, __shfl_xor(mm, 32, 64));
            tv = mm;
            if (val == mm) val = -3.4e38f;   // ties pop together: tau shrinks -> superset
        }
        thr[i] = tv - KEY_EPS2;
    }

    // pass 2: collect survivor indices (pk keys, same bits as pass 1)
    for (int it = 0; it < 32; ++it) {
        int m = it * 256 + lane * 4;
        float4 X = *(const float4*)(px + m);
        float4 Y = *(const float4*)(py + m);
        float4 Z = *(const float4*)(pz + m);
        float4 S = *(const float4*)(sb + m);
        float n0s = -S.x, n1s = -S.y, n2s = -S.z, n3s = -S.w;
        #pragma unroll
        for (int p = 0; p < 4; ++p) {
            int lq0 = wid * 8 + 2 * p, lq1 = lq0 + 1;
            float t0 = thr[2*p], t1 = thr[2*p+1];
            v2f k0 = fma2(tqx2[p], sp2(X.x), fma2(tqy2[p], sp2(Y.x), fma2(tqz2[p], sp2(Z.x), sp2(n0s))));
            v2f k1 = fma2(tqx2[p], sp2(X.y), fma2(tqy2[p], sp2(Y.y), fma2(tqz2[p], sp2(Z.y), sp2(n1s))));
            v2f k2 = fma2(tqx2[p], sp2(X.z), fma2(tqy2[p], sp2(Y.z), fma2(tqz2[p], sp2(Z.z), sp2(n2s))));
            v2f k3 = fma2(tqx2[p], sp2(X.w), fma2(tqy2[p], sp2(Y.w), fma2(tqz2[p], sp2(Z.w), sp2(n3s))));
            if (k0.x >= t0) { int s_ = atomicAdd(&cnt[lq0],1); if (s_<SCAP) sidx[lq0][s_] = (unsigned short)m; }
            if (k1.x >= t0) { int s_ = atomicAdd(&cnt[lq0],1); if (s_<SCAP) sidx[lq0][s_] = (unsigned short)(m+1); }
            if (k2.x >= t0) { int s_ = atomicAdd(&cnt[lq0],1); if (s_<SCAP) sidx[lq0][s_] = (unsigned short)(m+2); }
            if (k3.x >= t0) { int s_ = atomicAdd(&cnt[lq0],1); if (s_<SCAP) sidx[lq0][s_] = (unsigned short)(m+3); }
            if (k0.y >= t1) { int s_ = atomicAdd(&cnt[lq1],1); if (s_<SCAP) sidx[lq1][s_] = (unsigned short)m; }
            if (k1.y >= t1) { int s_ = atomicAdd(&cnt[lq1],1); if (s_<SCAP) sidx[lq1][s_] = (unsigned short)(m+1); }
            if (k2.y >= t1) { int s_ = atomicAdd(&cnt[lq1],1); if (s_<SCAP) sidx[lq1][s_] = (unsigned short)(m+2); }
            if (k3.y >= t1) { int s_ = atomicAdd(&cnt[lq1],1); if (s_<SCAP) sidx[lq1][s_] = (unsigned short)(m+3); }
        }
    }

    // phase A: exact reference key per survivor (scattered L2 loads, rare)
    #pragma unroll 1
    for (int i = 0; i < 8; ++i) {
        int lq = wid * 8 + i;
        int S = cnt[lq]; if (S > SCAP) S = SCAP;
        for (int p = lane; p < S; p += 64) {
            int m = sidx[lq][p];
            skey[lq][p] = negd2(qxs[i], qys[i], qzs[i], sqs[i],
                                px[m], py[m], pz[m], sb[m]);
        }
    }

    // phase B: exact rerank; ties -> lower index (lax.top_k semantics)
    #pragma unroll 1
    for (int i = 0; i < 8; ++i) {
        int lq = wid * 8 + i;
        int S = cnt[lq]; if (S > SCAP) S = SCAP;
        for (int p = lane; p < S; p += 64) {
            int m = sidx[lq][p];
            float km = skey[lq][p];
            int rank = 0;
            for (int j = 0; j < S; ++j) {
                float kj = skey[lq][j];
                int ij = sidx[lq][j];
                if (kj > km || (kj == km && ij < m)) rank++;
            }
            if (rank < KNN) outI[lq][rank] = m;
        }
    }
    __syncthreads();
    // write out 32 queries x 16 ranks
    #pragma unroll
    for (int h = 0; h < 2; ++h) {
        int lq = h * 16 + (t >> 4);
        idxo[(size_t)(qblk + lq) * KNN + (t & 15)] = outI[lq][t & 15];
    }
}

// ---------------- K2: gather + GEMM (8x4 micro) + fused BN-stats -------------
// R13 arithmetic: k_conv is LDS-pipe-saturated (DS-cycle count matches dur).
// 8q x 4d micro-tile: 3 ds_read_b128 per 32 FMA vs 2 per 16 -> 0.75x DS reads.
// 64q x 64d tile, 128 threads, grid 512 = 2 blocks/CU (4 waves/CU).
// Per-output accumulation order (j outer, c ascending) unchanged => bit-stable.
#define CPAD 68
__global__ __launch_bounds__(128) void k_conv(const float* __restrict__ xT,
                                              const float* __restrict__ Fb,
                                              const int* __restrict__ idx,
                                              float* __restrict__ outp,
                                              float* __restrict__ sums) {
    __shared__ float At[64][CPAD];    // 17.4 KB
    __shared__ float Bt[64 * 64];     // 16 KB
    int t = threadIdx.x;              // 0..127
    int q0 = blockIdx.x * 64;         // tile base (same batch: 8192%64==0)
    int bbase = q0 & ~(NPTS - 1);     // batch row offset in xT
    int qi0 = (t >> 4) * 8;           // 8 q-groups: 0..56
    int dj0 = (t & 15) * 4;           // 16 d-groups: 0..60
    int r = t & 63;                   // gather row
    int h = t >> 6;                   // row half (32 channels each)

    float acc[8][4];
    #pragma unroll
    for (int a = 0; a < 8; ++a)
        #pragma unroll
        for (int bb = 0; bb < 4; ++bb) acc[a][bb] = 0.f;

    for (int j = 0; j < 17; ++j) {
        // ---- stage A: 2 threads per row, 32 channels each, store transposed --
        {
            int qg = q0 + r;
            int nbr = (j < 16) ? (idx[(size_t)qg * KNN + j] & (NPTS - 1))
                               : (qg & (NPTS - 1));
            const float* src = xT + ((size_t)(bbase + nbr) * 64 + h * 32);
            #pragma unroll
            for (int s = 0; s < 8; ++s) {
                float4 v = *(const float4*)(src + s * 4);
                int c0 = h * 32 + s * 4;
                At[c0 + 0][r] = v.x;
                At[c0 + 1][r] = v.y;
                At[c0 + 2][r] = v.z;
                At[c0 + 3][r] = v.w;
            }
        }
        // ---- stage B: copy F[j] (4096 floats, 32 per thread) ----
        {
            const float* fj = Fb + j * 4096;
            #pragma unroll
            for (int u = 0; u < 8; ++u) {
                int e = u * 512 + t * 4;
                *(float4*)&Bt[e] = *(const float4*)(fj + e);
            }
        }
        __syncthreads();
        // ---- compute: 64 k-steps, 8x4 micro ----
        #pragma unroll 8
        for (int k = 0; k < 64; ++k) {
            float4 a0 = *(const float4*)&At[k][qi0];
            float4 a1 = *(const float4*)&At[k][qi0 + 4];
            float4 bv = *(const float4*)&Bt[k * 64 + dj0];
            float aq[8] = {a0.x, a0.y, a0.z, a0.w, a1.x, a1.y, a1.z, a1.w};
            #pragma unroll
            for (int qq = 0; qq < 8; ++qq) {
                acc[qq][0] = fmaf(aq[qq], bv.x, acc[qq][0]);
                acc[qq][1] = fmaf(aq[qq], bv.y, acc[qq][1]);
                acc[qq][2] = fmaf(aq[qq], bv.z, acc[qq][2]);
                acc[qq][3] = fmaf(aq[qq], bv.w, acc[qq][3]);
            }
        }
        __syncthreads();
    }
    // ---- epilogue 1: store outputs (8 rows x 4 d per thread) ----
    #pragma unroll
    for (int qq = 0; qq < 8; ++qq) {
        float4 o = make_float4(acc[qq][0], acc[qq][1], acc[qq][2], acc[qq][3]);
        *(float4*)(outp + (size_t)(q0 + qi0 + qq) * 64 + dj0) = o;
    }
    // ---- epilogue 2: fused BN stats (reuse Bt: P=sum, P2=sumsq; 8 q-groups) --
    {
        float* P  = Bt;          // [8][64]
        float* P2 = Bt + 512;    // [8][64]
        int g = t >> 4;          // q-group 0..7
        #pragma unroll
        for (int dd = 0; dd < 4; ++dd) {
            float sv = acc[0][dd];
            float qv = acc[0][dd] * acc[0][dd];
            #pragma unroll
            for (int qq = 1; qq < 8; ++qq) {
                sv += acc[qq][dd];
                qv = fmaf(acc[qq][dd], acc[qq][dd], qv);
            }
            P [g * 64 + dj0 + dd] = sv;
            P2[g * 64 + dj0 + dd] = qv;
        }
        __syncthreads();
        if (t < 64) {
            float a = 0.f, b2 = 0.f;
            #pragma unroll
            for (int gg = 0; gg < 8; ++gg) {
                a  += P [gg * 64 + t];
                b2 += P2[gg * 64 + t];
            }
            atomicAdd(&sums[t], a);
            atomicAdd(&sums[64 + t], b2);
        }
    }
}

// ---------------- K3: BN + transpose (B,N,D) -> (B,D,N) ----------------
__global__ __launch_bounds__(256) void k_bn(const float* __restrict__ outp,
                                            const float* __restrict__ sums,
                                            const float* __restrict__ gamma,
                                            const float* __restrict__ beta,
                                            float* __restrict__ out) {
    __shared__ float tile[64][65];
    __shared__ float sa[64], sb[64];
    int lane = threadIdx.x & 63, wid = threadIdx.x >> 6;
    int b = blockIdx.x >> 7, nt = blockIdx.x & 127;
    int n0 = nt * 64;
    if (threadIdx.x < 64) {
        const float inv = 1.f / 32768.f;
        float mean = sums[threadIdx.x] * inv;
        float var = sums[64 + threadIdx.x] * inv - mean * mean;
        float rs = rsqrtf(var + 1e-5f);
        float a = rs * gamma[threadIdx.x];
        sa[threadIdx.x] = a;
        sb[threadIdx.x] = beta[threadIdx.x] - mean * a;
    }
    for (int rr = 0; rr < 16; ++rr) {
        int r = wid * 16 + rr;
        tile[r][lane] = outp[((size_t)(b * NPTS + n0 + r)) * 64 + lane];
    }
    __syncthreads();
    for (int rr = 0; rr < 16; ++rr) {
        int dr = wid * 16 + rr;
        out[((size_t)b * 64 + dr) * NPTS + n0 + lane] =
            fmaf(tile[lane][dr], sa[dr], sb[dr]);
    }
}

extern "C" void kernel_launch(void* const* d_in, const int* in_sizes, int n_in,
                              void* d_out, int out_size, void* d_ws, size_t ws_size,
                              hipStream_t stream) {
    (void)in_sizes; (void)n_in; (void)out_size; (void)ws_size;
    const float* x     = (const float*)d_in[0];  // (4,64,8192)
    const float* pos   = (const float*)d_in[1];  // (4,3,8192)
    const float* F     = (const float*)d_in[2];  // (16,64,64)
    const float* gamma = (const float*)d_in[3];  // (64,)
    const float* beta  = (const float*)d_in[4];  // (64,)
    float* out = (float*)d_out;                  // (4,64,8192)

    char* ws = (char*)d_ws;
    float* xT   = (float*)(ws + OFF_XT);
    float* Fb   = (float*)(ws + OFF_FBIG);
    float* sums = (float*)(ws + OFF_SUMS);
    int*   idx  = (int*)(ws + OFF_IDX);
    float* pre  = (float*)(ws + OFF_PRE);
    float* sqa  = (float*)(ws + OFF_SQ);   // aliases pre; consumed before conv

    k_prep<<<658, 256, 0, stream>>>(x, F, pos, xT, Fb, sums, sqa);
    k_knn<<<1024, 256, 0, stream>>>(pos, sqa, idx);
    k_conv<<<512, 128, 0, stream>>>(xT, Fb, idx, pre, sums);
    k_bn<<<512, 256, 0, stream>>>(pre, sums, gamma, beta, out);
}

// Round 15
// 286.118 us; speedup vs baseline: 1.1020x; 1.1020x over previous
//
#include <hip/hip_runtime.h>
#include <hip/hip_bf16.h>

// Problem constants (B=4, C=64, N=8192, K=16, D=64)
#define NPTS 8192
#define NQ   32768      // B*N
#define KNN  16
#define SCAP 112        // survivor cap per query (expected ~25-50)

// ws layout (bytes)
#define OFF_XT   0                      // B*N*C f32 = 8 MB  (x transposed to (B,N,C))
#define OFF_FBIG (8*1024*1024)          // 17*64*64 f32 = 278528 B (F with appended -sum(F))
#define OFF_SUMS (OFF_FBIG + 278528)    // 128 f32 (sum, sumsq per channel)
#define OFF_IDX  (OFF_SUMS + 512)       // B*N*16 int32 = 2 MB
#define OFF_PRE  (OFF_IDX + 2*1024*1024)// B*N*64 f32 = 8 MB (pre-BN output, (B*N, D))
// sq array (B*N f32 = 128 KB) ALIASES the start of PRE: k_prep writes it,
// k_knn consumes it, then k_conv overwrites PRE — stream-ordered, safe.
#define OFF_SQ   OFF_PRE

typedef float v2f __attribute__((ext_vector_type(2)));
__device__ __forceinline__ v2f sp2(float v) { return (v2f){v, v}; }
__device__ __forceinline__ v2f fma2(v2f a, v2f b, v2f c) {
    return __builtin_elementwise_fma(a, b, c);
}
__device__ __forceinline__ v2f max2(v2f a, v2f b) {
    return __builtin_elementwise_max(a, b);
}

// Reference fp32 key — numpy execution model (verified R6, absmax 0.0156):
//   sq[m]   = (x*x + y*y) + z*z                  -- non-fused (np.sum(pos*pos))
//   inner   = fma(z,z', fma(y,y', rnd(x*x')))    -- einsum AVX2 axpy FMA chain
//   negd    = ((2*inner) - sq_n) - sq_m          -- elementwise, left-to-right
__device__ __forceinline__ float sq3(float x, float y, float z) {
    #pragma clang fp contract(off)
    float xx = x * x;
    float yy = y * y;
    float zz = z * z;
    return (xx + yy) + zz;
}
__device__ __forceinline__ float negd2(float qx, float qy, float qz, float sqn,
                                       float mx, float my, float mz, float sqm) {
    #pragma clang fp contract(off)
    float p0 = qx * mx;
    float inn = __builtin_fmaf(qz, mz, __builtin_fmaf(qy, my, p0));
    float t = 2.0f * inn;
    float u = t - sqn;
    return u - sqm;
}
// Filter margin: cheap fused key c~ = 2<q,m> - sqm differs from (exact key +
// sqn) by <= ~1e-4. 2e-3 is 20x conservative; two eps-steps cover tau-side
// and member-side error -> survivor set provably supersets the true top-16.
#define KEY_EPS2 2.0e-3f

// ---------------- K0: merged prep (transpose x | Fbig | zero sums | sq) ------
__global__ __launch_bounds__(256) void k_prep(const float* __restrict__ x,
                                              const float* __restrict__ F,
                                              const float* __restrict__ pos,
                                              float* __restrict__ xT,
                                              float* __restrict__ Fb,
                                              float* __restrict__ sums,
                                              float* __restrict__ sqa) {
    int bid = blockIdx.x;
    if (bid < 512) {
        __shared__ float tile[64][65];
        int lane = threadIdx.x & 63, wid = threadIdx.x >> 6;
        int b = bid >> 7, nt = bid & 127;
        int n0 = nt * 64;
        for (int rr = 0; rr < 16; ++rr) {
            int c = wid * 16 + rr;
            tile[c][lane] = x[((size_t)b * 64 + c) * NPTS + n0 + lane];
        }
        __syncthreads();
        for (int rr = 0; rr < 16; ++rr) {
            int r = wid * 16 + rr;
            xT[((size_t)(b * NPTS + n0 + r)) * 64 + lane] = tile[lane][r];
        }
    } else if (bid < 528) {
        int j = bid - 512;
        for (int e = threadIdx.x; e < 4096; e += 256)
            Fb[j * 4096 + e] = F[j * 4096 + e];
    } else if (bid == 528) {
        for (int e = threadIdx.x; e < 4096; e += 256) {
            float s = 0.f;
            for (int k = 0; k < 16; ++k) s += F[k * 4096 + e];
            Fb[16 * 4096 + e] = -s;
        }
    } else if (bid == 529) {
        if (threadIdx.x < 128) sums[threadIdx.x] = 0.f;
    } else {
        int g = (bid - 530) * 256 + threadIdx.x;   // 0..NQ-1
        int b = g >> 13, n = g & (NPTS - 1);
        const float* pb = pos + (size_t)b * 3 * NPTS;
        sqa[g] = sq3(pb[n], pb[NPTS + n], pb[2 * NPTS + n]);
    }
}

// ---------------- K1: kNN, 8 q/wave, pk key math + rotating prefetch ---------
// R14 lesson: pk math cut VALU busy 86->74 µs but dur didn't follow — the
// kernel went latency-bound at 16 waves/CU. Fix: explicit rotating software
// pipeline — iteration i+1's four float4 loads issue before iteration i's
// compute, so loads stay in flight across the whole pass.
__global__ __launch_bounds__(256, 4) void k_knn(const float* __restrict__ pos,
                                                const float* __restrict__ sqa,
                                                int* __restrict__ idxo) {
    __shared__ int            cnt[32];
    __shared__ unsigned short sidx[32][SCAP];
    __shared__ float          skey[32][SCAP];
    __shared__ int            outI[32][16];
    int t = threadIdx.x, lane = t & 63, wid = t >> 6;
    int qblk = blockIdx.x * 32;               // 32 queries per block, same batch
    int b = qblk >> 13;
    const float* px = pos + (size_t)b * 3 * NPTS;
    const float* py = px + NPTS;
    const float* pz = py + NPTS;
    const float* sb = sqa + (size_t)b * NPTS;
    int n0 = (qblk & (NPTS - 1)) + wid * 8;   // this wave's first query

    float qxs[8], qys[8], qzs[8], sqs[8];
    #pragma unroll
    for (int i = 0; i < 8; ++i) {
        qxs[i] = px[n0 + i]; qys[i] = py[n0 + i]; qzs[i] = pz[n0 + i];
        sqs[i] = sb[n0 + i];
    }
    v2f tqx2[4], tqy2[4], tqz2[4];
    #pragma unroll
    for (int p = 0; p < 4; ++p) {
        tqx2[p] = (v2f){2.0f * qxs[2*p], 2.0f * qxs[2*p+1]};
        tqy2[p] = (v2f){2.0f * qys[2*p], 2.0f * qys[2*p+1]};
        tqz2[p] = (v2f){2.0f * qzs[2*p], 2.0f * qzs[2*p+1]};
    }
    if (lane < 8) cnt[wid * 8 + lane] = 0;    // wave-private lists
    if (lane < 16) {
        #pragma unroll
        for (int i = 0; i < 8; ++i) outI[wid * 8 + i][lane] = n0 + i;  // fallback
    }

    int m0 = lane * 4;
    // pass 1: per-lane max of cheap key per query pair (pk math, prefetched)
    v2f lm2[4];
    #pragma unroll
    for (int p = 0; p < 4; ++p) lm2[p] = sp2(-3.4e38f);
    {
        float4 X = *(const float4*)(px + m0);
        float4 Y = *(const float4*)(py + m0);
        float4 Z = *(const float4*)(pz + m0);
        float4 S = *(const float4*)(sb + m0);
        for (int it = 0; it < 32; ++it) {
            int mn = ((it + 1) & 31) * 256 + m0;    // wrap: last prefetch unused
            float4 Xn = *(const float4*)(px + mn);
            float4 Yn = *(const float4*)(py + mn);
            float4 Zn = *(const float4*)(pz + mn);
            float4 Sn = *(const float4*)(sb + mn);
            float nx0 = -S.x, nx1 = -S.y, nx2 = -S.z, nx3 = -S.w;
            #pragma unroll
            for (int p = 0; p < 4; ++p) {
                v2f k0 = fma2(tqx2[p], sp2(X.x), fma2(tqy2[p], sp2(Y.x), fma2(tqz2[p], sp2(Z.x), sp2(nx0))));
                v2f k1 = fma2(tqx2[p], sp2(X.y), fma2(tqy2[p], sp2(Y.y), fma2(tqz2[p], sp2(Z.y), sp2(nx1))));
                v2f k2 = fma2(tqx2[p], sp2(X.z), fma2(tqy2[p], sp2(Y.z), fma2(tqz2[p], sp2(Z.z), sp2(nx2))));
                v2f k3 = fma2(tqx2[p], sp2(X.w), fma2(tqy2[p], sp2(Y.w), fma2(tqz2[p], sp2(Z.w), sp2(nx3))));
                v2f m01 = max2(k0, k1), m23 = max2(k2, k3);
                lm2[p] = max2(lm2[p], max2(m01, m23));
            }
            X = Xn; Y = Yn; Z = Zn; S = Sn;
        }
    }

    // thr[i] = (16th largest of 64 lane maxima) - 2*eps
    float thr[8];
    #pragma unroll
    for (int i = 0; i < 8; ++i) {
        float val = (i & 1) ? lm2[i >> 1].y : lm2[i >> 1].x;
        float tv = 0.f;
        for (int r = 0; r < 16; ++r) {
            float mm = val;
            mm = fmaxf(mm, __shfl_xor(mm, 1, 64));
            mm = fmaxf(mm, __shfl_xor(mm, 2, 64));
            mm = fmaxf(mm, __shfl_xor(mm, 4, 64));
            mm = fmaxf(mm, __shfl_xor(mm, 8, 64));
            mm = fmaxf(mm, __shfl_xor(mm, 16, 64));
            mm = fmaxf(mm, __shfl_xor(mm, 32, 64));
            tv = mm;
            if (val == mm) val = -3.4e38f;   // ties pop together: tau shrinks -> superset
        }
        thr[i] = tv - KEY_EPS2;
    }

    // pass 2: collect survivor indices (pk keys, same bits; prefetched)
    {
        float4 X = *(const float4*)(px + m0);
        float4 Y = *(const float4*)(py + m0);
        float4 Z = *(const float4*)(pz + m0);
        float4 S = *(const float4*)(sb + m0);
        for (int it = 0; it < 32; ++it) {
            int m = it * 256 + m0;
            int mn = ((it + 1) & 31) * 256 + m0;
            float4 Xn = *(const float4*)(px + mn);
            float4 Yn = *(const float4*)(py + mn);
            float4 Zn = *(const float4*)(pz + mn);
            float4 Sn = *(const float4*)(sb + mn);
            float nx0 = -S.x, nx1 = -S.y, nx2 = -S.z, nx3 = -S.w;
            #pragma unroll
            for (int p = 0; p < 4; ++p) {
                int lq0 = wid * 8 + 2 * p, lq1 = lq0 + 1;
                float t0 = thr[2*p], t1 = thr[2*p+1];
                v2f k0 = fma2(tqx2[p], sp2(X.x), fma2(tqy2[p], sp2(Y.x), fma2(tqz2[p], sp2(Z.x), sp2(nx0))));
                v2f k1 = fma2(tqx2[p], sp2(X.y), fma2(tqy2[p], sp2(Y.y), fma2(tqz2[p], sp2(Z.y), sp2(nx1))));
                v2f k2 = fma2(tqx2[p], sp2(X.z), fma2(tqy2[p], sp2(Y.z), fma2(tqz2[p], sp2(Z.z), sp2(nx2))));
                v2f k3 = fma2(tqx2[p], sp2(X.w), fma2(tqy2[p], sp2(Y.w), fma2(tqz2[p], sp2(Z.w), sp2(nx3))));
                if (k0.x >= t0) { int s_ = atomicAdd(&cnt[lq0],1); if (s_<SCAP) sidx[lq0][s_] = (unsigned short)m; }
                if (k1.x >= t0) { int s_ = atomicAdd(&cnt[lq0],1); if (s_<SCAP) sidx[lq0][s_] = (unsigned short)(m+1); }
                if (k2.x >= t0) { int s_ = atomicAdd(&cnt[lq0],1); if (s_<SCAP) sidx[lq0][s_] = (unsigned short)(m+2); }
                if (k3.x >= t0) { int s_ = atomicAdd(&cnt[lq0],1); if (s_<SCAP) sidx[lq0][s_] = (unsigned short)(m+3); }
                if (k0.y >= t1) { int s_ = atomicAdd(&cnt[lq1],1); if (s_<SCAP) sidx[lq1][s_] = (unsigned short)m; }
                if (k1.y >= t1) { int s_ = atomicAdd(&cnt[lq1],1); if (s_<SCAP) sidx[lq1][s_] = (unsigned short)(m+1); }
                if (k2.y >= t1) { int s_ = atomicAdd(&cnt[lq1],1); if (s_<SCAP) sidx[lq1][s_] = (unsigned short)(m+2); }
                if (k3.y >= t1) { int s_ = atomicAdd(&cnt[lq1],1); if (s_<SCAP) sidx[lq1][s_] = (unsigned short)(m+3); }
            }
            X = Xn; Y = Yn; Z = Zn; S = Sn;
        }
    }

    // phase A: exact reference key per survivor (scattered L2 loads, rare)
    #pragma unroll 1
    for (int i = 0; i < 8; ++i) {
        int lq = wid * 8 + i;
        int S = cnt[lq]; if (S > SCAP) S = SCAP;
        for (int p = lane; p < S; p += 64) {
            int m = sidx[lq][p];
            skey[lq][p] = negd2(qxs[i], qys[i], qzs[i], sqs[i],
                                px[m], py[m], pz[m], sb[m]);
        }
    }

    // phase B: exact rerank; ties -> lower index (lax.top_k semantics)
    #pragma unroll 1
    for (int i = 0; i < 8; ++i) {
        int lq = wid * 8 + i;
        int S = cnt[lq]; if (S > SCAP) S = SCAP;
        for (int p = lane; p < S; p += 64) {
            int m = sidx[lq][p];
            float km = skey[lq][p];
            int rank = 0;
            for (int j = 0; j < S; ++j) {
                float kj = skey[lq][j];
                int ij = sidx[lq][j];
                if (kj > km || (kj == km && ij < m)) rank++;
            }
            if (rank < KNN) outI[lq][rank] = m;
        }
    }
    __syncthreads();
    // write out 32 queries x 16 ranks
    #pragma unroll
    for (int h = 0; h < 2; ++h) {
        int lq = h * 16 + (t >> 4);
        idxo[(size_t)(qblk + lq) * KNN + (t & 15)] = outI[lq][t & 15];
    }
}

// ---------------- K2: gather + GEMM + fused BN-stats (R13 proven) ------------
// 64q x 64d tile, 256 threads, 4x4 micro, 2 blocks/CU. R10/R14 both showed
// 128-thread variants regress (occupancy cliff) — keep this shape.
#define CPAD 68
__global__ __launch_bounds__(256) void k_conv(const float* __restrict__ xT,
                                              const float* __restrict__ Fb,
                                              const int* __restrict__ idx,
                                              float* __restrict__ outp,
                                              float* __restrict__ sums) {
    __shared__ float At[64][CPAD];
    __shared__ float Bt[64 * 64];
    int t = threadIdx.x;
    int q0 = blockIdx.x * 64;                 // tile base (same batch: 8192%64==0)
    int bbase = q0 & ~(NPTS - 1);             // batch row offset in xT
    int qi0 = (t >> 4) * 4;                   // query sub-block 0..60
    int dj0 = (t & 15) * 4;                   // d sub-block 0..60
    int r = t & 63;                           // gather row
    int s = t >> 6;                           // 16-float segment

    float acc[4][4];
    #pragma unroll
    for (int a = 0; a < 4; ++a)
        #pragma unroll
        for (int bb = 0; bb < 4; ++bb) acc[a][bb] = 0.f;

    for (int j = 0; j < 17; ++j) {
        // ---- stage A: gather 64 neighbor rows, store transposed ----
        {
            int qg = q0 + r;
            int nbr = (j < 16) ? (idx[(size_t)qg * KNN + j] & (NPTS - 1))
                               : (qg & (NPTS - 1));
            const float* src = xT + ((size_t)(bbase + nbr) * 64 + s * 16);
            float4 v0 = *(const float4*)(src);
            float4 v1 = *(const float4*)(src + 4);
            float4 v2 = *(const float4*)(src + 8);
            float4 v3 = *(const float4*)(src + 12);
            int c0 = s * 16;
            At[c0+ 0][r] = v0.x; At[c0+ 1][r] = v0.y; At[c0+ 2][r] = v0.z; At[c0+ 3][r] = v0.w;
            At[c0+ 4][r] = v1.x; At[c0+ 5][r] = v1.y; At[c0+ 6][r] = v1.z; At[c0+ 7][r] = v1.w;
            At[c0+ 8][r] = v2.x; At[c0+ 9][r] = v2.y; At[c0+10][r] = v2.z; At[c0+11][r] = v2.w;
            At[c0+12][r] = v3.x; At[c0+13][r] = v3.y; At[c0+14][r] = v3.z; At[c0+15][r] = v3.w;
        }
        // ---- stage B: copy F[j] (4096 floats) ----
        {
            const float* fj = Fb + j * 4096;
            #pragma unroll
            for (int u = 0; u < 4; ++u) {
                int e = u * 1024 + t * 4;
                *(float4*)&Bt[e] = *(const float4*)(fj + e);
            }
        }
        __syncthreads();
        // ---- compute: 64 k-steps ----
        #pragma unroll 8
        for (int k = 0; k < 64; ++k) {
            float4 av = *(const float4*)&At[k][qi0];
            float4 bv = *(const float4*)&Bt[k * 64 + dj0];
            acc[0][0] = fmaf(av.x, bv.x, acc[0][0]);
            acc[0][1] = fmaf(av.x, bv.y, acc[0][1]);
            acc[0][2] = fmaf(av.x, bv.z, acc[0][2]);
            acc[0][3] = fmaf(av.x, bv.w, acc[0][3]);
            acc[1][0] = fmaf(av.y, bv.x, acc[1][0]);
            acc[1][1] = fmaf(av.y, bv.y, acc[1][1]);
            acc[1][2] = fmaf(av.y, bv.z, acc[1][2]);
            acc[1][3] = fmaf(av.y, bv.w, acc[1][3]);
            acc[2][0] = fmaf(av.z, bv.x, acc[2][0]);
            acc[2][1] = fmaf(av.z, bv.y, acc[2][1]);
            acc[2][2] = fmaf(av.z, bv.z, acc[2][2]);
            acc[2][3] = fmaf(av.z, bv.w, acc[2][3]);
            acc[3][0] = fmaf(av.w, bv.x, acc[3][0]);
            acc[3][1] = fmaf(av.w, bv.y, acc[3][1]);
            acc[3][2] = fmaf(av.w, bv.z, acc[3][2]);
            acc[3][3] = fmaf(av.w, bv.w, acc[3][3]);
        }
        __syncthreads();
    }
    // ---- epilogue 1: store outputs ----
    #pragma unroll
    for (int qi = 0; qi < 4; ++qi) {
        float4 o = make_float4(acc[qi][0], acc[qi][1], acc[qi][2], acc[qi][3]);
        *(float4*)(outp + (size_t)(q0 + qi0 + qi) * 64 + dj0) = o;
    }
    // ---- epilogue 2: fused BN stats (reuse Bt: P=sum, P2=sumsq; 16 q-groups) ----
    {
        float* P  = Bt;          // [16][64]
        float* P2 = Bt + 1024;   // [16][64]
        int g = t >> 4;          // q-group 0..15
        #pragma unroll
        for (int dd = 0; dd < 4; ++dd) {
            float sv = ((acc[0][dd] + acc[1][dd]) + acc[2][dd]) + acc[3][dd];
            float qv = fmaf(acc[3][dd], acc[3][dd],
                       fmaf(acc[2][dd], acc[2][dd],
                       fmaf(acc[1][dd], acc[1][dd], acc[0][dd] * acc[0][dd])));
            P [g * 64 + dj0 + dd] = sv;
            P2[g * 64 + dj0 + dd] = qv;
        }
        __syncthreads();
        if (t < 64) {
            float a = 0.f, b2 = 0.f;
            #pragma unroll
            for (int gg = 0; gg < 16; ++gg) {
                a  += P [gg * 64 + t];
                b2 += P2[gg * 64 + t];
            }
            atomicAdd(&sums[t], a);
            atomicAdd(&sums[64 + t], b2);
        }
    }
}

// ---------------- K3: BN + transpose (B,N,D) -> (B,D,N) ----------------
__global__ __launch_bounds__(256) void k_bn(const float* __restrict__ outp,
                                            const float* __restrict__ sums,
                                            const float* __restrict__ gamma,
                                            const float* __restrict__ beta,
                                            float* __restrict__ out) {
    __shared__ float tile[64][65];
    __shared__ float sa[64], sb[64];
    int lane = threadIdx.x & 63, wid = threadIdx.x >> 6;
    int b = blockIdx.x >> 7, nt = blockIdx.x & 127;
    int n0 = nt * 64;
    if (threadIdx.x < 64) {
        const float inv = 1.f / 32768.f;
        float mean = sums[threadIdx.x] * inv;
        float var = sums[64 + threadIdx.x] * inv - mean * mean;
        float rs = rsqrtf(var + 1e-5f);
        float a = rs * gamma[threadIdx.x];
        sa[threadIdx.x] = a;
        sb[threadIdx.x] = beta[threadIdx.x] - mean * a;
    }
    for (int rr = 0; rr < 16; ++rr) {
        int r = wid * 16 + rr;
        tile[r][lane] = outp[((size_t)(b * NPTS + n0 + r)) * 64 + lane];
    }
    __syncthreads();
    for (int rr = 0; rr < 16; ++rr) {
        int dr = wid * 16 + rr;
        out[((size_t)b * 64 + dr) * NPTS + n0 + lane] =
            fmaf(tile[lane][dr], sa[dr], sb[dr]);
    }
}

extern "C" void kernel_launch(void* const* d_in, const int* in_sizes, int n_in,
                              void* d_out, int out_size, void* d_ws, size_t ws_size,
                              hipStream_t stream) {
    (void)in_sizes; (void)n_in; (void)out_size; (void)ws_size;
    const float* x     = (const float*)d_in[0];  // (4,64,8192)
    const float* pos   = (const float*)d_in[1];  // (4,3,8192)
    const float* F     = (const float*)d_in[2];  // (16,64,64)
    const float* gamma = (const float*)d_in[3];  // (64,)
    const float* beta  = (const float*)d_in[4];  // (64,)
    float* out = (float*)d_out;                  // (4,64,8192)

    char* ws = (char*)d_ws;
    float* xT   = (float*)(ws + OFF_XT);
    float* Fb   = (float*)(ws + OFF_FBIG);
    float* sums = (float*)(ws + OFF_SUMS);
    int*   idx  = (int*)(ws + OFF_IDX);
    float* pre  = (float*)(ws + OFF_PRE);
    float* sqa  = (float*)(ws + OFF_SQ);   // aliases pre; consumed before conv

    k_prep<<<658, 256, 0, stream>>>(x, F, pos, xT, Fb, sums, sqa);
    k_knn<<<1024, 256, 0, stream>>>(pos, sqa, idx);
    k_conv<<<512, 256, 0, stream>>>(xT, Fb, idx, pre, sums);
    k_bn<<<512, 256, 0, stream>>>(pre, sums, gamma, beta, out);
}

// Round 18
// 281.635 us; speedup vs baseline: 1.1196x; 1.0159x over previous
//
#include <hip/hip_runtime.h>
#include <hip/hip_bf16.h>

// Problem constants (B=4, C=64, N=8192, K=16, D=64)
#define NPTS 8192
#define NQ   32768      // B*N
#define KNN  16
#define SCAP 112        // survivor cap per query (expected ~25-50)

// ws layout (bytes)
#define OFF_XT   0                      // B*N*C f32 = 8 MB  (x transposed to (B,N,C))
#define OFF_FBIG (8*1024*1024)          // 17*64*64 f32 = 278528 B (F with appended -sum(F))
#define OFF_SUMS (OFF_FBIG + 278528)    // 128 f32 (sum, sumsq per channel)
#define OFF_IDX  (OFF_SUMS + 512)       // B*N*16 int32 = 2 MB
#define OFF_PRE  (OFF_IDX + 2*1024*1024)// B*N*64 f32 = 8 MB (pre-BN output, (B*N, D))
// sq array (B*N f32 = 128 KB) ALIASES the start of PRE: k_prep writes it,
// k_knn consumes it, then k_conv overwrites PRE — stream-ordered, safe.
#define OFF_SQ   OFF_PRE

// Reference fp32 key — numpy execution model (verified R6, absmax 0.0156):
//   sq[m]   = (x*x + y*y) + z*z                  -- non-fused (np.sum(pos*pos))
//   inner   = fma(z,z', fma(y,y', rnd(x*x')))    -- einsum AVX2 axpy FMA chain
//   negd    = ((2*inner) - sq_n) - sq_m          -- elementwise, left-to-right
__device__ __forceinline__ float sq3(float x, float y, float z) {
    #pragma clang fp contract(off)
    float xx = x * x;
    float yy = y * y;
    float zz = z * z;
    return (xx + yy) + zz;
}
__device__ __forceinline__ float negd2(float qx, float qy, float qz, float sqn,
                                       float mx, float my, float mz, float sqm) {
    #pragma clang fp contract(off)
    float p0 = qx * mx;
    float inn = __builtin_fmaf(qz, mz, __builtin_fmaf(qy, my, p0));
    float t = 2.0f * inn;
    float u = t - sqn;
    return u - sqm;
}
// Filter margin: cheap fused key c~ = 2<q,m> - sqm differs from (exact key +
// sqn) by <= ~1e-4. 2e-3 is 20x conservative; two eps-steps cover tau-side
// and member-side error -> survivor set provably supersets the true top-16.
#define KEY_EPS2 2.0e-3f

// ---------------- K0: merged prep (transpose x | Fbig | zero sums | sq) ------
// blocks 0..511: transpose x. 512..527: Fbig j. 528: Fbig[16]=-sum. 529: zero
// sums. 530..657: sq per point (exact reference rounding).
__global__ __launch_bounds__(256) void k_prep(const float* __restrict__ x,
                                              const float* __restrict__ F,
                                              const float* __restrict__ pos,
                                              float* __restrict__ xT,
                                              float* __restrict__ Fb,
                                              float* __restrict__ sums,
                                              float* __restrict__ sqa) {
    int bid = blockIdx.x;
    if (bid < 512) {
        __shared__ float tile[64][65];
        int lane = threadIdx.x & 63, wid = threadIdx.x >> 6;
        int b = bid >> 7, nt = bid & 127;
        int n0 = nt * 64;
        for (int rr = 0; rr < 16; ++rr) {
            int c = wid * 16 + rr;
            tile[c][lane] = x[((size_t)b * 64 + c) * NPTS + n0 + lane];
        }
        __syncthreads();
        for (int rr = 0; rr < 16; ++rr) {
            int r = wid * 16 + rr;
            xT[((size_t)(b * NPTS + n0 + r)) * 64 + lane] = tile[lane][r];
        }
    } else if (bid < 528) {
        int j = bid - 512;
        for (int e = threadIdx.x; e < 4096; e += 256)
            Fb[j * 4096 + e] = F[j * 4096 + e];
    } else if (bid == 528) {
        for (int e = threadIdx.x; e < 4096; e += 256) {
            float s = 0.f;
            for (int k = 0; k < 16; ++k) s += F[k * 4096 + e];
            Fb[16 * 4096 + e] = -s;
        }
    } else if (bid == 529) {
        if (threadIdx.x < 128) sums[threadIdx.x] = 0.f;
    } else {
        int g = (bid - 530) * 256 + threadIdx.x;   // 0..NQ-1
        int b = g >> 13, n = g & (NPTS - 1);
        const float* pb = pos + (size_t)b * 3 * NPTS;
        sqa[g] = sq3(pb[n], pb[NPTS + n], pb[2 * NPTS + n]);
    }
}

// ---------------- K1: kNN, 8 q/wave, L2 streaming (R13 proven best) ----------
// Scalar cheap-key passes (3 FMA + max3 tree per cand), ushort sidx,
// __launch_bounds__(256,4). R14 pk-math and R15 prefetch were both neutral or
// worse; R16/R17 MFMA filter failed (fragment-layout uncertainty) — this is
// the banked best structure (139 µs).
__global__ __launch_bounds__(256, 4) void k_knn(const float* __restrict__ pos,
                                                const float* __restrict__ sqa,
                                                int* __restrict__ idxo) {
    __shared__ int            cnt[32];
    __shared__ unsigned short sidx[32][SCAP];
    __shared__ float          skey[32][SCAP];
    __shared__ int            outI[32][16];
    int t = threadIdx.x, lane = t & 63, wid = t >> 6;
    int qblk = blockIdx.x * 32;               // 32 queries per block, same batch
    int b = qblk >> 13;
    const float* px = pos + (size_t)b * 3 * NPTS;
    const float* py = px + NPTS;
    const float* pz = py + NPTS;
    const float* sb = sqa + (size_t)b * NPTS;
    int n0 = (qblk & (NPTS - 1)) + wid * 8;   // this wave's first query

    float qxs[8], qys[8], qzs[8], sqs[8], tqx[8], tqy[8], tqz[8];
    #pragma unroll
    for (int i = 0; i < 8; ++i) {
        qxs[i] = px[n0 + i]; qys[i] = py[n0 + i]; qzs[i] = pz[n0 + i];
        sqs[i] = sb[n0 + i];
        tqx[i] = 2.0f * qxs[i]; tqy[i] = 2.0f * qys[i]; tqz[i] = 2.0f * qzs[i];
    }
    if (lane < 8) cnt[wid * 8 + lane] = 0;    // wave-private lists
    if (lane < 16) {
        #pragma unroll
        for (int i = 0; i < 8; ++i) outI[wid * 8 + i][lane] = n0 + i;  // fallback
    }

    // pass 1: per-lane max of cheap key (3 FMA/cand; max3-friendly tree)
    float lm[8];
    #pragma unroll
    for (int i = 0; i < 8; ++i) lm[i] = -3.4e38f;
    for (int it = 0; it < 32; ++it) {
        int m = it * 256 + lane * 4;
        float4 X = *(const float4*)(px + m);
        float4 Y = *(const float4*)(py + m);
        float4 Z = *(const float4*)(pz + m);
        float4 S = *(const float4*)(sb + m);
        #pragma unroll
        for (int i = 0; i < 8; ++i) {
            float a0 = __builtin_fmaf(tqx[i], X.x, __builtin_fmaf(tqy[i], Y.x, __builtin_fmaf(tqz[i], Z.x, -S.x)));
            float a1 = __builtin_fmaf(tqx[i], X.y, __builtin_fmaf(tqy[i], Y.y, __builtin_fmaf(tqz[i], Z.y, -S.y)));
            float a2 = __builtin_fmaf(tqx[i], X.z, __builtin_fmaf(tqy[i], Y.z, __builtin_fmaf(tqz[i], Z.z, -S.z)));
            float a3 = __builtin_fmaf(tqx[i], X.w, __builtin_fmaf(tqy[i], Y.w, __builtin_fmaf(tqz[i], Z.w, -S.w)));
            // v_max3 x2: max3(a0,a1,a2), then max3(that,a3,lm)
            float m012 = fmaxf(fmaxf(a0, a1), a2);
            lm[i] = fmaxf(fmaxf(m012, a3), lm[i]);
        }
    }

    // thr[i] = (16th largest of 64 lane maxima) - 2*eps
    float thr[8];
    #pragma unroll
    for (int i = 0; i < 8; ++i) {
        float val = lm[i], tv = 0.f;
        for (int r = 0; r < 16; ++r) {
            float mm = val;
            mm = fmaxf(mm, __shfl_xor(mm, 1, 64));
            mm = fmaxf(mm, __shfl_xor(mm, 2, 64));
            mm = fmaxf(mm, __shfl_xor(mm, 4, 64));
            mm = fmaxf(mm, __shfl_xor(mm, 8, 64));
            mm = fmaxf(mm, __shfl_xor(mm, 16, 64));
            mm = fmaxf(mm, __shfl_xor(mm, 32, 64));
            tv = mm;
            if (val == mm) val = -3.4e38f;   // ties pop together: tau shrinks -> superset
        }
        thr[i] = tv - KEY_EPS2;
    }

    // pass 2: collect survivor indices (hits rare -> execz-skipped bodies)
    for (int it = 0; it < 32; ++it) {
        int m = it * 256 + lane * 4;
        float4 X = *(const float4*)(px + m);
        float4 Y = *(const float4*)(py + m);
        float4 Z = *(const float4*)(pz + m);
        float4 S = *(const float4*)(sb + m);
        #pragma unroll
        for (int i = 0; i < 8; ++i) {
            int lq = wid * 8 + i;
            float a0 = __builtin_fmaf(tqx[i], X.x, __builtin_fmaf(tqy[i], Y.x, __builtin_fmaf(tqz[i], Z.x, -S.x)));
            float a1 = __builtin_fmaf(tqx[i], X.y, __builtin_fmaf(tqy[i], Y.y, __builtin_fmaf(tqz[i], Z.y, -S.y)));
            float a2 = __builtin_fmaf(tqx[i], X.z, __builtin_fmaf(tqy[i], Y.z, __builtin_fmaf(tqz[i], Z.z, -S.z)));
            float a3 = __builtin_fmaf(tqx[i], X.w, __builtin_fmaf(tqy[i], Y.w, __builtin_fmaf(tqz[i], Z.w, -S.w)));
            if (a0 >= thr[i]) { int s_ = atomicAdd(&cnt[lq],1); if (s_<SCAP) sidx[lq][s_] = (unsigned short)m; }
            if (a1 >= thr[i]) { int s_ = atomicAdd(&cnt[lq],1); if (s_<SCAP) sidx[lq][s_] = (unsigned short)(m+1); }
            if (a2 >= thr[i]) { int s_ = atomicAdd(&cnt[lq],1); if (s_<SCAP) sidx[lq][s_] = (unsigned short)(m+2); }
            if (a3 >= thr[i]) { int s_ = atomicAdd(&cnt[lq],1); if (s_<SCAP) sidx[lq][s_] = (unsigned short)(m+3); }
        }
    }

    // phase A: exact reference key per survivor (scattered L2 loads, rare)
    #pragma unroll 1
    for (int i = 0; i < 8; ++i) {
        int lq = wid * 8 + i;
        int S = cnt[lq]; if (S > SCAP) S = SCAP;
        for (int p = lane; p < S; p += 64) {
            int m = sidx[lq][p];
            skey[lq][p] = negd2(qxs[i], qys[i], qzs[i], sqs[i],
                                px[m], py[m], pz[m], sb[m]);
        }
    }

    // phase B: exact rerank; ties -> lower index (lax.top_k semantics)
    #pragma unroll 1
    for (int i = 0; i < 8; ++i) {
        int lq = wid * 8 + i;
        int S = cnt[lq]; if (S > SCAP) S = SCAP;
        for (int p = lane; p < S; p += 64) {
            int m = sidx[lq][p];
            float km = skey[lq][p];
            int rank = 0;
            for (int j = 0; j < S; ++j) {
                float kj = skey[lq][j];
                int ij = sidx[lq][j];
                if (kj > km || (kj == km && ij < m)) rank++;
            }
            if (rank < KNN) outI[lq][rank] = m;
        }
    }
    __syncthreads();
    // write out 32 queries x 16 ranks
    #pragma unroll
    for (int h = 0; h < 2; ++h) {
        int lq = h * 16 + (t >> 4);
        idxo[(size_t)(qblk + lq) * KNN + (t & 15)] = outI[lq][t & 15];
    }
}

// ---------------- K2: gather + GEMM + fused BN-stats epilogue ----------------
// outp[q][d] = sum_{j=0..16} sum_c xT[nbr_j(q)][c] * Fbig[j][c][d]
// Tile: 64 q x 64 d, 256 threads, 4x4 micro (R9/R13 proven). Epilogue computes
// block-partial per-channel sum/sumsq from live accumulators (reusing Bt).
// R10/R14 both showed 128-thread variants regress (occupancy cliff).
#define CPAD 68
__global__ __launch_bounds__(256) void k_conv(const float* __restrict__ xT,
                                              const float* __restrict__ Fb,
                                              const int* __restrict__ idx,
                                              float* __restrict__ outp,
                                              float* __restrict__ sums) {
    __shared__ float At[64][CPAD];
    __shared__ float Bt[64 * 64];
    int t = threadIdx.x;
    int q0 = blockIdx.x * 64;                 // tile base (same batch: 8192%64==0)
    int bbase = q0 & ~(NPTS - 1);             // batch row offset in xT
    int qi0 = (t >> 4) * 4;                   // query sub-block 0..60
    int dj0 = (t & 15) * 4;                   // d sub-block 0..60
    int r = t & 63;                           // gather row
    int s = t >> 6;                           // 16-float segment

    float acc[4][4];
    #pragma unroll
    for (int a = 0; a < 4; ++a)
        #pragma unroll
        for (int bb = 0; bb < 4; ++bb) acc[a][bb] = 0.f;

    for (int j = 0; j < 17; ++j) {
        // ---- stage A: gather 64 neighbor rows, store transposed ----
        {
            int qg = q0 + r;
            int nbr = (j < 16) ? (idx[(size_t)qg * KNN + j] & (NPTS - 1))
                               : (qg & (NPTS - 1));
            const float* src = xT + ((size_t)(bbase + nbr) * 64 + s * 16);
            float4 v0 = *(const float4*)(src);
            float4 v1 = *(const float4*)(src + 4);
            float4 v2 = *(const float4*)(src + 8);
            float4 v3 = *(const float4*)(src + 12);
            int c0 = s * 16;
            At[c0+ 0][r] = v0.x; At[c0+ 1][r] = v0.y; At[c0+ 2][r] = v0.z; At[c0+ 3][r] = v0.w;
            At[c0+ 4][r] = v1.x; At[c0+ 5][r] = v1.y; At[c0+ 6][r] = v1.z; At[c0+ 7][r] = v1.w;
            At[c0+ 8][r] = v2.x; At[c0+ 9][r] = v2.y; At[c0+10][r] = v2.z; At[c0+11][r] = v2.w;
            At[c0+12][r] = v3.x; At[c0+13][r] = v3.y; At[c0+14][r] = v3.z; At[c0+15][r] = v3.w;
        }
        // ---- stage B: copy F[j] (4096 floats) ----
        {
            const float* fj = Fb + j * 4096;
            #pragma unroll
            for (int u = 0; u < 4; ++u) {
                int e = u * 1024 + t * 4;
                *(float4*)&Bt[e] = *(const float4*)(fj + e);
            }
        }
        __syncthreads();
        // ---- compute: 64 k-steps ----
        #pragma unroll 8
        for (int k = 0; k < 64; ++k) {
            float4 av = *(const float4*)&At[k][qi0];
            float4 bv = *(const float4*)&Bt[k * 64 + dj0];
            acc[0][0] = fmaf(av.x, bv.x, acc[0][0]);
            acc[0][1] = fmaf(av.x, bv.y, acc[0][1]);
            acc[0][2] = fmaf(av.x, bv.z, acc[0][2]);
            acc[0][3] = fmaf(av.x, bv.w, acc[0][3]);
            acc[1][0] = fmaf(av.y, bv.x, acc[1][0]);
            acc[1][1] = fmaf(av.y, bv.y, acc[1][1]);
            acc[1][2] = fmaf(av.y, bv.z, acc[1][2]);
            acc[1][3] = fmaf(av.y, bv.w, acc[1][3]);
            acc[2][0] = fmaf(av.z, bv.x, acc[2][0]);
            acc[2][1] = fmaf(av.z, bv.y, acc[2][1]);
            acc[2][2] = fmaf(av.z, bv.z, acc[2][2]);
            acc[2][3] = fmaf(av.z, bv.w, acc[2][3]);
            acc[3][0] = fmaf(av.w, bv.x, acc[3][0]);
            acc[3][1] = fmaf(av.w, bv.y, acc[3][1]);
            acc[3][2] = fmaf(av.w, bv.z, acc[3][2]);
            acc[3][3] = fmaf(av.w, bv.w, acc[3][3]);
        }
        __syncthreads();
    }
    // ---- epilogue 1: store outputs ----
    #pragma unroll
    for (int qi = 0; qi < 4; ++qi) {
        float4 o = make_float4(acc[qi][0], acc[qi][1], acc[qi][2], acc[qi][3]);
        *(float4*)(outp + (size_t)(q0 + qi0 + qi) * 64 + dj0) = o;
    }
    // ---- epilogue 2: fused BN stats (reuse Bt: P=sum, P2=sumsq; 16 q-groups) ----
    {
        float* P  = Bt;          // [16][64]
        float* P2 = Bt + 1024;   // [16][64]
        int g = t >> 4;          // q-group 0..15
        #pragma unroll
        for (int dd = 0; dd < 4; ++dd) {
            float sv = ((acc[0][dd] + acc[1][dd]) + acc[2][dd]) + acc[3][dd];
            float qv = fmaf(acc[3][dd], acc[3][dd],
                       fmaf(acc[2][dd], acc[2][dd],
                       fmaf(acc[1][dd], acc[1][dd], acc[0][dd] * acc[0][dd])));
            P [g * 64 + dj0 + dd] = sv;
            P2[g * 64 + dj0 + dd] = qv;
        }
        __syncthreads();
        if (t < 64) {
            float a = 0.f, b2 = 0.f;
            #pragma unroll
            for (int gg = 0; gg < 16; ++gg) {
                a  += P [gg * 64 + t];
                b2 += P2[gg * 64 + t];
            }
            atomicAdd(&sums[t], a);
            atomicAdd(&sums[64 + t], b2);
        }
    }
}

// ---------------- K3: BN + transpose (B,N,D) -> (B,D,N) ----------------
__global__ __launch_bounds__(256) void k_bn(const float* __restrict__ outp,
                                            const float* __restrict__ sums,
                                            const float* __restrict__ gamma,
                                            const float* __restrict__ beta,
                                            float* __restrict__ out) {
    __shared__ float tile[64][65];
    __shared__ float sa[64], sb[64];
    int lane = threadIdx.x & 63, wid = threadIdx.x >> 6;
    int b = blockIdx.x >> 7, nt = blockIdx.x & 127;
    int n0 = nt * 64;
    if (threadIdx.x < 64) {
        const float inv = 1.f / 32768.f;
        float mean = sums[threadIdx.x] * inv;
        float var = sums[64 + threadIdx.x] * inv - mean * mean;
        float rs = rsqrtf(var + 1e-5f);
        float a = rs * gamma[threadIdx.x];
        sa[threadIdx.x] = a;
        sb[threadIdx.x] = beta[threadIdx.x] - mean * a;
    }
    for (int rr = 0; rr < 16; ++rr) {
        int r = wid * 16 + rr;
        tile[r][lane] = outp[((size_t)(b * NPTS + n0 + r)) * 64 + lane];
    }
    __syncthreads();
    for (int rr = 0; rr < 16; ++rr) {
        int dr = wid * 16 + rr;
        out[((size_t)b * 64 + dr) * NPTS + n0 + lane] =
            fmaf(tile[lane][dr], sa[dr], sb[dr]);
    }
}

extern "C" void kernel_launch(void* const* d_in, const int* in_sizes, int n_in,
                              void* d_out, int out_size, void* d_ws, size_t ws_size,
                              hipStream_t stream) {
    (void)in_sizes; (void)n_in; (void)out_size; (void)ws_size;
    const float* x     = (const float*)d_in[0];  // (4,64,8192)
    const float* pos   = (const float*)d_in[1];  // (4,3,8192)
    const float* F     = (const float*)d_in[2];  // (16,64,64)
    const float* gamma = (const float*)d_in[3];  // (64,)
    const float* beta  = (const float*)d_in[4];  // (64,)
    float* out = (float*)d_out;                  // (4,64,8192)

    char* ws = (char*)d_ws;
    float* xT   = (float*)(ws + OFF_XT);
    float* Fb   = (float*)(ws + OFF_FBIG);
    float* sums = (float*)(ws + OFF_SUMS);
    int*   idx  = (int*)(ws + OFF_IDX);
    float* pre  = (float*)(ws + OFF_PRE);
    float* sqa  = (float*)(ws + OFF_SQ);   // aliases pre; consumed before conv

    k_prep<<<658, 256, 0, stream>>>(x, F, pos, xT, Fb, sums, sqa);
    k_knn<<<1024, 256, 0, stream>>>(pos, sqa, idx);
    k_conv<<<512, 256, 0, stream>>>(xT, Fb, idx, pre, sums);
    k_bn<<<512, 256, 0, stream>>>(pre, sums, gamma, beta, out);
}